// Round 3
// baseline (329.491 us; speedup 1.0000x reference)
//
#include <hip/hip_runtime.h>

// BindingFormer fused pipeline for MI355X (gfx950), round 3.
// Changes vs r2: edge_k M=128/block (halves L2 B-stream), features parallelized
// across all waves, B register double-buffering, LDS-staged coalesced f32 out;
// rep_k rewritten 8-nodes/block (amortize weight reads); frames+wg1+swz2 merged.

typedef __attribute__((ext_vector_type(8))) short short8;  // 8 x bf16 (4 VGPRs)
typedef __attribute__((ext_vector_type(4))) float f32x4;   // MFMA accumulator

#define TWO_PI 6.283185307179586f
#define E_AB_TOT 131072

// ws layout (bytes)
#define WS_RT    0         // frames: 1024 x 12 f32            = 49152
#define WS_WG1   49152     // composed geom weight 27x256 f32  = 27648
#define WS_REPB  76800     // rep bf16 1024x256                = 524288
#define WS_W1F   601088    // swizzled W1' 19*16*64*8 bf16     = 311296
#define WS_W2F   912384    // swizzled W2  8*8*64*8 bf16       = 65536

__device__ __forceinline__ unsigned short f2bf(float x){
  unsigned int u = __float_as_uint(x);
  u += 0x7fffu + ((u >> 16) & 1u);            // RTNE
  return (unsigned short)(u >> 16);
}

__device__ __forceinline__ float gelu_t(float x){
  float z = 0.7978845608028654f * (x + 0.044715f * x * x * x);
  float e = __expf(2.0f * z);
  float t = 1.0f - 2.0f / (e + 1.0f);         // tanh(z), robust at +/-inf
  return 0.5f * x * (1.0f + t);
}

// ---------- merged prep: frames (blk 0-3) | wg1 (blk 4-30) | swz2 (blk 31-46)
__global__ __launch_bounds__(256) void prep1_k(
    const float* __restrict__ coords, float* __restrict__ RT,
    const float* __restrict__ wg, const float* __restrict__ w1e, float* __restrict__ wg1,
    const float* __restrict__ w2e, unsigned short* __restrict__ w2f){
  int blk = blockIdx.x, tid = threadIdx.x;
  if (blk < 4){                       // frames
    int n = blk * 256 + tid;
    const float* p = coords + n * 9;
    float ax=p[0],ay=p[1],az=p[2], bx=p[3],by=p[4],bz=p[5], cx=p[6],cy=p[7],cz=p[8];
    float v1x=cx-bx, v1y=cy-by, v1z=cz-bz;
    float v2x=ax-bx, v2y=ay-by, v2z=az-bz;
    float n1 = sqrtf(v1x*v1x+v1y*v1y+v1z*v1z) + 1e-6f;
    float e1x=v1x/n1, e1y=v1y/n1, e1z=v1z/n1;
    float dp = e1x*v2x + e1y*v2y + e1z*v2z;
    float u2x=v2x-e1x*dp, u2y=v2y-e1y*dp, u2z=v2z-e1z*dp;
    float n2 = sqrtf(u2x*u2x+u2y*u2y+u2z*u2z) + 1e-6f;
    float e2x=u2x/n2, e2y=u2y/n2, e2z=u2z/n2;
    float* r = RT + n * 12;
    r[0]=e1x; r[1]=e2x; r[2]=e1y*e2z - e1z*e2y;
    r[3]=e1y; r[4]=e2y; r[5]=e1z*e2x - e1x*e2z;
    r[6]=e1z; r[7]=e2z; r[8]=e1x*e2y - e1y*e2x;
    r[9]=bx;  r[10]=by; r[11]=bz;
  } else if (blk < 31){               // wg1: 27x256 = w_geom @ w1e[0:128]
    int r = blk - 4;
    float acc = 0.f;
    for (int j = 0; j < 128; ++j) acc += wg[r * 128 + j] * w1e[j * 256 + tid];
    wg1[r * 256 + tid] = acc;
  } else {                            // swz2: W2 (256x128) -> B-frag order
    int u = (blk - 31) * 4 + (tid >> 6);   // 0..63
    int lane = tid & 63;
    int s = u >> 3, c = u & 7;
    int n  = c * 16 + (lane & 15);
    int kb = s * 32 + (lane >> 4) * 8;
    unsigned short* o = w2f + (((s * 8 + c) * 64) + lane) * 8;
    for (int j = 0; j < 8; ++j)
      o[j] = f2bf(w2e[(kb + j) * 128 + n]);
  }
}

// ---------- swz1: W1' (608x256) -> B-frag order (depends on wg1) ----------
// K layout: [0:27 geom (Wg1) | 27:91 rope (w1e 128:192) | 91:96 zero
//            | 96:352 rep_src (w1e 192:448) | 352:608 rep_dst (w1e 448:704)]
__global__ __launch_bounds__(256) void swz1_k(
    const float* __restrict__ wg1, const float* __restrict__ w1e, unsigned short* __restrict__ w1f){
  int u = blockIdx.x * 4 + (threadIdx.x >> 6);   // 0..303
  int lane = threadIdx.x & 63;
  int s = u >> 4, c = u & 15;
  int n  = c * 16 + (lane & 15);
  int kb = s * 32 + (lane >> 4) * 8;
  unsigned short* o = w1f + (((s * 16 + c) * 64) + lane) * 8;
  for (int j = 0; j < 8; ++j){
    int k = kb + j;
    float val;
    if      (k < 27)  val = wg1[k * 256 + n];
    else if (k < 91)  val = w1e[(128 + k - 27)  * 256 + n];
    else if (k < 96)  val = 0.f;
    else if (k < 352) val = w1e[(192 + k - 96)  * 256 + n];
    else              val = w1e[(448 + k - 352) * 256 + n];
    o[j] = f2bf(val);
  }
}

// ---------- node MLP: 8 nodes/block, weights amortized -------------------
__global__ __launch_bounds__(256) void rep2_k(
    const float* __restrict__ emb, const float* __restrict__ ts,
    const float* __restrict__ tf,  const float* __restrict__ w1,
    const float* __restrict__ b1,  const float* __restrict__ w2,
    const float* __restrict__ b2,  unsigned short* __restrict__ repb){
  __shared__ float xt[288 * 12];   // xt[k][nd], pad 12 (48B rows, 16B-aligned)
  __shared__ float ht[256 * 12];
  int tid = threadIdx.x, n0 = blockIdx.x * 8;
  #pragma unroll
  for (int nd = 0; nd < 8; ++nd)
    xt[tid * 12 + nd] = emb[(n0 + nd) * 256 + tid];
  {
    int nd = tid >> 5, j = tid & 31;
    float ang = TWO_PI * ts[n0 + nd] * tf[j & 15];
    float s, c; __sincosf(ang, &s, &c);
    xt[(256 + j) * 12 + nd] = (j < 16) ? s : c;
  }
  __syncthreads();
  float acc[8];
  float bias1 = b1[tid];
  #pragma unroll
  for (int nd = 0; nd < 8; ++nd) acc[nd] = bias1;
  #pragma unroll 4
  for (int k = 0; k < 288; ++k){
    float w = w1[k * 256 + tid];
    f32x4 xa = *(const f32x4*)&xt[k * 12];
    f32x4 xb = *(const f32x4*)&xt[k * 12 + 4];
    acc[0] += xa[0]*w; acc[1] += xa[1]*w; acc[2] += xa[2]*w; acc[3] += xa[3]*w;
    acc[4] += xb[0]*w; acc[5] += xb[1]*w; acc[6] += xb[2]*w; acc[7] += xb[3]*w;
  }
  #pragma unroll
  for (int nd = 0; nd < 8; ++nd) ht[tid * 12 + nd] = gelu_t(acc[nd]);
  __syncthreads();
  float acc2[8];
  float bias2 = b2[tid];
  #pragma unroll
  for (int nd = 0; nd < 8; ++nd) acc2[nd] = bias2;
  #pragma unroll 4
  for (int k = 0; k < 256; ++k){
    float w = w2[k * 256 + tid];
    f32x4 ha = *(const f32x4*)&ht[k * 12];
    f32x4 hb = *(const f32x4*)&ht[k * 12 + 4];
    acc2[0] += ha[0]*w; acc2[1] += ha[1]*w; acc2[2] += ha[2]*w; acc2[3] += ha[3]*w;
    acc2[4] += hb[0]*w; acc2[5] += hb[1]*w; acc2[6] += hb[2]*w; acc2[7] += hb[3]*w;
  }
  #pragma unroll
  for (int nd = 0; nd < 8; ++nd)
    repb[(n0 + nd) * 256 + tid] = f2bf(acc2[nd] + xt[tid * 12 + nd]);  // residual
}

// ---------- fused edge kernel: 128 edges/block, 1024 threads (16 waves) ----
// LDS edge_in 128x616 bf16 (stride 1232 B); GEMM1 K=608 -> gelu -> H (aliased)
// -> GEMM2 K=256 -> O staged f32 (stride 136) -> coalesced stores.
__global__ __launch_bounds__(1024, 4) void edge_k(
    const unsigned short* __restrict__ repb, const float* __restrict__ RT,
    const float* __restrict__ cf,
    const int* __restrict__ resi, const int* __restrict__ chain,
    const int* __restrict__ gia,  const int* __restrict__ gib,
    const int* __restrict__ pid,
    const unsigned short* __restrict__ w1f, const unsigned short* __restrict__ w2f,
    const float* __restrict__ b1, const float* __restrict__ b2,
    float* __restrict__ outp)
{
  __shared__ __align__(16) char smem[157696];  // 128 rows x 1232 B
  __shared__ int lsrc[128];
  __shared__ int ldst[128];

  int tid = threadIdx.x;
  int e0  = blockIdx.x * 128;

  if (tid < 128){
    int e = e0 + tid, s_, d_;
    if (e < E_AB_TOT){ s_ = gia[e]; d_ = gib[e]; }
    else {
      int i = e - E_AB_TOT;
      int b = i >> 10, w_ = i & 1023;
      s_ = pid[b * 32 + (w_ >> 5)];
      d_ = pid[b * 32 + (w_ & 31)];
    }
    lsrc[tid] = s_; ldst[tid] = d_;
  }
  __syncthreads();

  // issue rep-gather loads (128 edges x 2 x 512 B), overlap with features
  uint4 g[8];
  int ged[8], gpart[8], goff[8];
  {
    const uint4* rep4 = (const uint4*)repb;
    #pragma unroll
    for (int i = 0; i < 8; ++i){
      int cid = tid + 1024 * i;
      ged[i] = cid >> 6; gpart[i] = (cid >> 5) & 1; goff[i] = cid & 31;
      int row = gpart[i] ? ldst[ged[i]] : lsrc[ged[i]];
      g[i] = rep4[row * 32 + goff[i]];
    }
  }

  // features: 8 threads/edge, 12 cols each (cols 0..95)
  {
    int ed = tid >> 3, slot = tid & 7;
    int s_ = lsrc[ed], d_ = ldst[ed];
    unsigned short* row = (unsigned short*)(smem + ed * 1232);
    float disp = ((float)resi[s_] - (float)resi[d_]) * 0.125f;
    float inv  = (chain[s_] == chain[d_]) ? 1.f / (fabsf(disp) + 1.f) : 0.f;
    const float* Rs = RT + s_ * 12;
    const float* Rd = RT + d_ * 12;
    float dx = Rd[9]-Rs[9], dy = Rd[10]-Rs[10], dz = Rd[11]-Rs[11];
    float dist = sqrtf(dx*dx + dy*dy + dz*dz + 1e-6f);
    float invd = 1.f / (dist + 1.f);
    #pragma unroll
    for (int q = 0; q < 12; ++q){
      int c = slot * 12 + q;
      float val;
      if (c < 15){                               // rbf
        float z = (dist - (float)c * (20.f / 14.f)) * (15.f / 20.f);
        val = __expf(-0.5f * z * z);
      } else if (c < 24){                        // relrot (a-major)
        int idx = c - 15, a = idx / 3, b_ = idx - a * 3;
        val = Rs[a]*Rd[b_] + Rs[3+a]*Rd[3+b_] + Rs[6+a]*Rd[6+b_];
      } else if (c < 27){                        // local
        int k = c - 24;
        val = (Rs[k]*dx + Rs[3+k]*dy + Rs[6+k]*dz) * invd;
      } else if (c < 91){                        // rope
        int j2 = c - 27;
        float ang = TWO_PI * disp * cf[j2 & 31];
        val = ((j2 < 32) ? __sinf(ang) : __cosf(ang)) * inv;
      } else val = 0.f;
      row[c] = f2bf(val);
    }
  }

  // store gathered rep rows (cols 96..607)
  #pragma unroll
  for (int i = 0; i < 8; ++i)
    *(uint4*)(smem + ged[i] * 1232 + 192 + gpart[i] * 512 + goff[i] * 16) = g[i];
  __syncthreads();

  // ---- GEMM1: (128x608) x (608x256) ----
  int w    = tid >> 6, lane = tid & 63;
  int rt   = w & 7;                 // 8 rowtiles
  int c0   = (w >> 3) * 8;          // 2 colgroups x 8 coltiles
  int mrow = rt * 16 + (lane & 15);
  int qoff = (lane >> 4) * 16;
  int quad = lane >> 4;
  f32x4 acc[8];
  #pragma unroll
  for (int c = 0; c < 8; ++c) acc[c] = (f32x4){0.f, 0.f, 0.f, 0.f};
  const short8* w1f8 = (const short8*)w1f;

  short8 bb0[4], bb1[4];
  {
    const short8* p = w1f8 + (c0) * 64 + lane;
    bb0[0]=p[0]; bb0[1]=p[64]; bb0[2]=p[128]; bb0[3]=p[192];
  }
  for (int s = 0; s < 19; ++s){
    short8 a = *(const short8*)(smem + mrow * 1232 + s * 64 + qoff);
    {  // prefetch group1 of s
      const short8* p = w1f8 + (s * 16 + c0 + 4) * 64 + lane;
      bb1[0]=p[0]; bb1[1]=p[64]; bb1[2]=p[128]; bb1[3]=p[192];
    }
    acc[0] = __builtin_amdgcn_mfma_f32_16x16x32_bf16(a, bb0[0], acc[0], 0, 0, 0);
    acc[1] = __builtin_amdgcn_mfma_f32_16x16x32_bf16(a, bb0[1], acc[1], 0, 0, 0);
    acc[2] = __builtin_amdgcn_mfma_f32_16x16x32_bf16(a, bb0[2], acc[2], 0, 0, 0);
    acc[3] = __builtin_amdgcn_mfma_f32_16x16x32_bf16(a, bb0[3], acc[3], 0, 0, 0);
    if (s + 1 < 19){  // prefetch group0 of s+1
      const short8* p = w1f8 + ((s + 1) * 16 + c0) * 64 + lane;
      bb0[0]=p[0]; bb0[1]=p[64]; bb0[2]=p[128]; bb0[3]=p[192];
    }
    acc[4] = __builtin_amdgcn_mfma_f32_16x16x32_bf16(a, bb1[0], acc[4], 0, 0, 0);
    acc[5] = __builtin_amdgcn_mfma_f32_16x16x32_bf16(a, bb1[1], acc[5], 0, 0, 0);
    acc[6] = __builtin_amdgcn_mfma_f32_16x16x32_bf16(a, bb1[2], acc[6], 0, 0, 0);
    acc[7] = __builtin_amdgcn_mfma_f32_16x16x32_bf16(a, bb1[3], acc[7], 0, 0, 0);
  }
  __syncthreads();   // edge_in reads done; alias LDS as H

  // H = gelu(acc + b1), stride 264 bf16 (528 B)
  unsigned short* H = (unsigned short*)smem;
  #pragma unroll
  for (int c = 0; c < 8; ++c){
    int n = (c0 + c) * 16 + (lane & 15);
    float bias = b1[n];
    #pragma unroll
    for (int r = 0; r < 4; ++r){
      int m = rt * 16 + quad * 4 + r;            // C/D: row = quad*4+reg, col = lane&15
      H[m * 264 + n] = f2bf(gelu_t(acc[c][r] + bias));
    }
  }
  __syncthreads();

  // ---- GEMM2: (128x256) x (256x128) ----
  int c20 = (w >> 3) * 4;
  f32x4 acc2[4];
  #pragma unroll
  for (int c = 0; c < 4; ++c) acc2[c] = (f32x4){0.f, 0.f, 0.f, 0.f};
  const short8* w2f8 = (const short8*)w2f;
  short8 cb0[2], cb1[2];
  {
    const short8* p = w2f8 + (c20) * 64 + lane;
    cb0[0]=p[0]; cb0[1]=p[64];
  }
  for (int s = 0; s < 8; ++s){
    short8 a = *(const short8*)(smem + mrow * 528 + s * 64 + qoff);
    {
      const short8* p = w2f8 + (s * 8 + c20 + 2) * 64 + lane;
      cb1[0]=p[0]; cb1[1]=p[64];
    }
    acc2[0] = __builtin_amdgcn_mfma_f32_16x16x32_bf16(a, cb0[0], acc2[0], 0, 0, 0);
    acc2[1] = __builtin_amdgcn_mfma_f32_16x16x32_bf16(a, cb0[1], acc2[1], 0, 0, 0);
    if (s + 1 < 8){
      const short8* p = w2f8 + ((s + 1) * 8 + c20) * 64 + lane;
      cb0[0]=p[0]; cb0[1]=p[64];
    }
    acc2[2] = __builtin_amdgcn_mfma_f32_16x16x32_bf16(a, cb1[0], acc2[2], 0, 0, 0);
    acc2[3] = __builtin_amdgcn_mfma_f32_16x16x32_bf16(a, cb1[1], acc2[3], 0, 0, 0);
  }
  __syncthreads();   // H reads done; alias LDS as O (f32, stride 136)

  float* O = (float*)smem;
  #pragma unroll
  for (int c = 0; c < 4; ++c){
    int n = (c20 + c) * 16 + (lane & 15);
    float bias = b2[n];
    float v0 = acc2[c][0] + bias, v1 = acc2[c][1] + bias;
    float v2 = acc2[c][2] + bias, v3 = acc2[c][3] + bias;
    int m = rt * 16 + quad * 4;
    O[(m+0) * 136 + n] = v0;
    O[(m+1) * 136 + n] = v1;
    O[(m+2) * 136 + n] = v2;
    O[(m+3) * 136 + n] = v3;
  }
  __syncthreads();
  // coalesced full-line stores: 128 rows x 512 B
  float* og = outp + (size_t)e0 * 128;
  #pragma unroll
  for (int i = 0; i < 4; ++i){
    int cid = tid + 1024 * i;
    int m = cid >> 5, ch = cid & 31;
    f32x4 v = *(const f32x4*)(O + m * 136 + ch * 4);
    *(f32x4*)(og + m * 128 + ch * 4) = v;
  }
}

extern "C" void kernel_launch(void* const* d_in, const int* in_sizes, int n_in,
                              void* d_out, int out_size, void* d_ws, size_t ws_size,
                              hipStream_t stream) {
  const float* emb    = (const float*)d_in[0];
  const float* ts     = (const float*)d_in[1];
  const float* coords = (const float*)d_in[2];
  const float* tf     = (const float*)d_in[3];
  const float* cf     = (const float*)d_in[4];
  const float* w1r    = (const float*)d_in[5];
  const float* b1r    = (const float*)d_in[6];
  const float* w2r    = (const float*)d_in[7];
  const float* b2r    = (const float*)d_in[8];
  const float* wg     = (const float*)d_in[9];
  const float* w1e    = (const float*)d_in[10];
  const float* b1e    = (const float*)d_in[11];
  const float* w2e    = (const float*)d_in[12];
  const float* b2e    = (const float*)d_in[13];
  const int* resi     = (const int*)d_in[14];
  const int* chain    = (const int*)d_in[15];
  const int* gia      = (const int*)d_in[16];
  const int* gib      = (const int*)d_in[17];
  const int* pid      = (const int*)d_in[18];

  char* ws = (char*)d_ws;
  float* RT            = (float*)(ws + WS_RT);
  float* WG1           = (float*)(ws + WS_WG1);
  unsigned short* REPB = (unsigned short*)(ws + WS_REPB);
  unsigned short* W1F  = (unsigned short*)(ws + WS_W1F);
  unsigned short* W2F  = (unsigned short*)(ws + WS_W2F);
  float* outp          = (float*)d_out;

  hipLaunchKernelGGL(prep1_k, dim3(47),   dim3(256),  0, stream,
                     coords, RT, wg, w1e, WG1, w2e, W2F);
  hipLaunchKernelGGL(rep2_k,  dim3(128),  dim3(256),  0, stream,
                     emb, ts, tf, w1r, b1r, w2r, b2r, REPB);
  hipLaunchKernelGGL(swz1_k,  dim3(76),   dim3(256),  0, stream, WG1, w1e, W1F);
  hipLaunchKernelGGL(edge_k,  dim3(1040), dim3(1024), 0, stream,
                     REPB, RT, cf, resi, chain, gia, gib, pid, W1F, W2F, b1e, b2e, outp);
}

// Round 4
// 256.626 us; speedup vs baseline: 1.2839x; 1.2839x over previous
//
#include <hip/hip_runtime.h>

// BindingFormer fused pipeline for MI355X (gfx950), round 4.
// r3 post-mortem: edge_k was bound by per-CU L2 B-frag delivery (16 waves x 8 KB
// = 128 KB/step = ~2300 cyc/step vs 620 cyc MFMA). Fix: wave tiles Mw=64 x Nw=32
// (2 rowgroups x 8 colgroups) -> B = 32 KB/step/CU, double-buffered in regs.
// Prep merged into ONE kernel (swz1 recomputes wg1 inline). Harness reset floor
// is ~110 us of dur_us and not addressable here.

typedef __attribute__((ext_vector_type(8))) short short8;  // 8 x bf16 (4 VGPRs)
typedef __attribute__((ext_vector_type(4))) float f32x4;   // MFMA accumulator

#define TWO_PI 6.283185307179586f
#define E_AB_TOT 131072

// ws layout (bytes)
#define WS_RT    0         // frames: 1024 x 12 f32            = 49152
#define WS_REPB  49152     // rep bf16 1024x256                = 524288
#define WS_W1F   573440    // swizzled W1' 19*16*64*8 bf16     = 311296
#define WS_W2F   884736    // swizzled W2  8*8*64*8 bf16       = 65536

__device__ __forceinline__ unsigned short f2bf(float x){
  unsigned int u = __float_as_uint(x);
  u += 0x7fffu + ((u >> 16) & 1u);            // RTNE
  return (unsigned short)(u >> 16);
}

__device__ __forceinline__ float gelu_t(float x){
  float z = 0.7978845608028654f * (x + 0.044715f * x * x * x);
  float e = __expf(2.0f * z);
  float t = 1.0f - 2.0f / (e + 1.0f);         // tanh(z), robust at +/-inf
  return 0.5f * x * (1.0f + t);
}

// ---------- merged prep: rep MLP (blk 0-127) | frames (128-131) |
//            swz2 (132-147) | swz1 w/ inline wg1 (148-223) -------------------
__global__ __launch_bounds__(256) void prep_k(
    const float* __restrict__ emb, const float* __restrict__ ts,
    const float* __restrict__ tf,  const float* __restrict__ w1,
    const float* __restrict__ b1,  const float* __restrict__ w2,
    const float* __restrict__ b2,  unsigned short* __restrict__ repb,
    const float* __restrict__ coords, float* __restrict__ RT,
    const float* __restrict__ wg, const float* __restrict__ w1e,
    unsigned short* __restrict__ w1f,
    const float* __restrict__ w2e, unsigned short* __restrict__ w2f){
  __shared__ float xt[288 * 12];   // rep part only
  __shared__ float ht[256 * 12];
  int blk = blockIdx.x, tid = threadIdx.x;
  if (blk < 128){                   // ---- node MLP, 8 nodes/block ----
    int n0 = blk * 8;
    #pragma unroll
    for (int nd = 0; nd < 8; ++nd)
      xt[tid * 12 + nd] = emb[(n0 + nd) * 256 + tid];
    {
      int nd = tid >> 5, j = tid & 31;
      float ang = TWO_PI * ts[n0 + nd] * tf[j & 15];
      float s, c; __sincosf(ang, &s, &c);
      xt[(256 + j) * 12 + nd] = (j < 16) ? s : c;
    }
    __syncthreads();
    float acc[8];
    float bias1 = b1[tid];
    #pragma unroll
    for (int nd = 0; nd < 8; ++nd) acc[nd] = bias1;
    #pragma unroll 4
    for (int k = 0; k < 288; ++k){
      float w = w1[k * 256 + tid];
      f32x4 xa = *(const f32x4*)&xt[k * 12];
      f32x4 xb = *(const f32x4*)&xt[k * 12 + 4];
      acc[0] += xa[0]*w; acc[1] += xa[1]*w; acc[2] += xa[2]*w; acc[3] += xa[3]*w;
      acc[4] += xb[0]*w; acc[5] += xb[1]*w; acc[6] += xb[2]*w; acc[7] += xb[3]*w;
    }
    #pragma unroll
    for (int nd = 0; nd < 8; ++nd) ht[tid * 12 + nd] = gelu_t(acc[nd]);
    __syncthreads();
    float acc2[8];
    float bias2 = b2[tid];
    #pragma unroll
    for (int nd = 0; nd < 8; ++nd) acc2[nd] = bias2;
    #pragma unroll 4
    for (int k = 0; k < 256; ++k){
      float w = w2[k * 256 + tid];
      f32x4 ha = *(const f32x4*)&ht[k * 12];
      f32x4 hb = *(const f32x4*)&ht[k * 12 + 4];
      acc2[0] += ha[0]*w; acc2[1] += ha[1]*w; acc2[2] += ha[2]*w; acc2[3] += ha[3]*w;
      acc2[4] += hb[0]*w; acc2[5] += hb[1]*w; acc2[6] += hb[2]*w; acc2[7] += hb[3]*w;
    }
    #pragma unroll
    for (int nd = 0; nd < 8; ++nd)
      repb[(n0 + nd) * 256 + tid] = f2bf(acc2[nd] + xt[tid * 12 + nd]);
  } else if (blk < 132){            // ---- frames ----
    int n = (blk - 128) * 256 + tid;
    const float* p = coords + n * 9;
    float ax=p[0],ay=p[1],az=p[2], bx=p[3],by=p[4],bz=p[5], cx=p[6],cy=p[7],cz=p[8];
    float v1x=cx-bx, v1y=cy-by, v1z=cz-bz;
    float v2x=ax-bx, v2y=ay-by, v2z=az-bz;
    float n1 = sqrtf(v1x*v1x+v1y*v1y+v1z*v1z) + 1e-6f;
    float e1x=v1x/n1, e1y=v1y/n1, e1z=v1z/n1;
    float dp = e1x*v2x + e1y*v2y + e1z*v2z;
    float u2x=v2x-e1x*dp, u2y=v2y-e1y*dp, u2z=v2z-e1z*dp;
    float n2 = sqrtf(u2x*u2x+u2y*u2y+u2z*u2z) + 1e-6f;
    float e2x=u2x/n2, e2y=u2y/n2, e2z=u2z/n2;
    float* r = RT + n * 12;
    r[0]=e1x; r[1]=e2x; r[2]=e1y*e2z - e1z*e2y;
    r[3]=e1y; r[4]=e2y; r[5]=e1z*e2x - e1x*e2z;
    r[6]=e1z; r[7]=e2z; r[8]=e1x*e2y - e1y*e2x;
    r[9]=bx;  r[10]=by; r[11]=bz;
  } else if (blk < 148){            // ---- swz2: W2 (256x128) -> B-frag ----
    int u = (blk - 132) * 4 + (tid >> 6);   // 0..63
    int lane = tid & 63;
    int s = u >> 3, c = u & 7;
    int n  = c * 16 + (lane & 15);
    int kb = s * 32 + (lane >> 4) * 8;
    unsigned short* o = w2f + (((s * 8 + c) * 64) + lane) * 8;
    for (int j = 0; j < 8; ++j)
      o[j] = f2bf(w2e[(kb + j) * 128 + n]);
  } else {                          // ---- swz1: W1' (608x256) -> B-frag ----
    // K: [0:27 geom=wg@w1e[0:128] | 27:91 rope (w1e 128:192) | 91:96 zero
    //     | 96:352 rep_src (192:448) | 352:608 rep_dst (448:704)]
    int u = (blk - 148) * 4 + (tid >> 6);   // 0..303
    int lane = tid & 63;
    int s = u >> 4, c = u & 15;
    int n  = c * 16 + (lane & 15);
    int kb = s * 32 + (lane >> 4) * 8;
    unsigned short* o = w1f + (((s * 16 + c) * 64) + lane) * 8;
    for (int j = 0; j < 8; ++j){
      int k = kb + j;
      float val;
      if (k < 27){                  // inline wg1: w_geom[k] . w1e[0:128, n]
        val = 0.f;
        for (int j2 = 0; j2 < 128; ++j2) val += wg[k * 128 + j2] * w1e[j2 * 256 + n];
      }
      else if (k < 91)  val = w1e[(128 + k - 27)  * 256 + n];
      else if (k < 96)  val = 0.f;
      else if (k < 352) val = w1e[(192 + k - 96)  * 256 + n];
      else              val = w1e[(448 + k - 352) * 256 + n];
      o[j] = f2bf(val);
    }
  }
}

// ---------- fused edge kernel: 128 edges/block, 1024 thr (16 waves) --------
// Wave tile Mw=64 x Nw=32: rowgroup = w&1 (4 rowtiles), colgroup = w>>1
// (2 coltiles GEMM1 / 1 coltile GEMM2). B per CU per step: 32 KB (was 128 KB).
__global__ __launch_bounds__(1024, 4) void edge_k(
    const unsigned short* __restrict__ repb, const float* __restrict__ RT,
    const float* __restrict__ cf,
    const int* __restrict__ resi, const int* __restrict__ chain,
    const int* __restrict__ gia,  const int* __restrict__ gib,
    const int* __restrict__ pid,
    const unsigned short* __restrict__ w1f, const unsigned short* __restrict__ w2f,
    const float* __restrict__ b1, const float* __restrict__ b2,
    float* __restrict__ outp)
{
  __shared__ __align__(16) char smem[157696];  // 128 rows x 1232 B edge_in
  __shared__ int lsrc[128];
  __shared__ int ldst[128];

  int tid = threadIdx.x;
  int e0  = blockIdx.x * 128;

  if (tid < 128){
    int e = e0 + tid, s_, d_;
    if (e < E_AB_TOT){ s_ = gia[e]; d_ = gib[e]; }
    else {
      int i = e - E_AB_TOT;
      int b = i >> 10, w_ = i & 1023;
      s_ = pid[b * 32 + (w_ >> 5)];
      d_ = pid[b * 32 + (w_ & 31)];
    }
    lsrc[tid] = s_; ldst[tid] = d_;
  }
  __syncthreads();

  // issue rep-gather loads (128 edges x 2 x 512 B), overlap with features
  uint4 g[8];
  int ged[8], gpart[8], goff[8];
  {
    const uint4* rep4 = (const uint4*)repb;
    #pragma unroll
    for (int i = 0; i < 8; ++i){
      int cid = tid + 1024 * i;
      ged[i] = cid >> 6; gpart[i] = (cid >> 5) & 1; goff[i] = cid & 31;
      int row = gpart[i] ? ldst[ged[i]] : lsrc[ged[i]];
      g[i] = rep4[row * 32 + goff[i]];
    }
  }

  // features: 8 threads/edge, 12 cols each (cols 0..95)
  {
    int ed = tid >> 3, slot = tid & 7;
    int s_ = lsrc[ed], d_ = ldst[ed];
    unsigned short* row = (unsigned short*)(smem + ed * 1232);
    float disp = ((float)resi[s_] - (float)resi[d_]) * 0.125f;
    float inv  = (chain[s_] == chain[d_]) ? 1.f / (fabsf(disp) + 1.f) : 0.f;
    const float* Rs = RT + s_ * 12;
    const float* Rd = RT + d_ * 12;
    float dx = Rd[9]-Rs[9], dy = Rd[10]-Rs[10], dz = Rd[11]-Rs[11];
    float dist = sqrtf(dx*dx + dy*dy + dz*dz + 1e-6f);
    float invd = 1.f / (dist + 1.f);
    #pragma unroll
    for (int q = 0; q < 12; ++q){
      int c = slot * 12 + q;
      float val;
      if (c < 15){                               // rbf
        float z = (dist - (float)c * (20.f / 14.f)) * (15.f / 20.f);
        val = __expf(-0.5f * z * z);
      } else if (c < 24){                        // relrot (a-major)
        int idx = c - 15, a = idx / 3, b_ = idx - a * 3;
        val = Rs[a]*Rd[b_] + Rs[3+a]*Rd[3+b_] + Rs[6+a]*Rd[6+b_];
      } else if (c < 27){                        // local
        int k = c - 24;
        val = (Rs[k]*dx + Rs[3+k]*dy + Rs[6+k]*dz) * invd;
      } else if (c < 91){                        // rope
        int j2 = c - 27;
        float ang = TWO_PI * disp * cf[j2 & 31];
        val = ((j2 < 32) ? __sinf(ang) : __cosf(ang)) * inv;
      } else val = 0.f;
      row[c] = f2bf(val);
    }
  }

  // store gathered rep rows (cols 96..607)
  #pragma unroll
  for (int i = 0; i < 8; ++i)
    *(uint4*)(smem + ged[i] * 1232 + 192 + gpart[i] * 512 + goff[i] * 16) = g[i];
  __syncthreads();

  // ---- GEMM1: (128x608) x (608x256) ----
  int w    = tid >> 6, lane = tid & 63;
  int rtb  = (w & 1) * 4;           // 4 rowtiles (64 rows)
  int c0   = (w >> 1) * 2;          // 2 coltiles (32 cols)
  int lr   = lane & 15;
  int quad = lane >> 4, qoff = quad * 16;
  f32x4 acc[8];                     // [c*4 + r]
  #pragma unroll
  for (int i = 0; i < 8; ++i) acc[i] = (f32x4){0.f, 0.f, 0.f, 0.f};
  const short8* w1f8 = (const short8*)w1f;

  short8 b0 = w1f8[(c0 + 0) * 64 + lane];
  short8 b1v = w1f8[(c0 + 1) * 64 + lane];
  for (int s = 0; s < 19; ++s){
    short8 a0 = *(const short8*)(smem + ((rtb+0)*16 + lr) * 1232 + s * 64 + qoff);
    short8 a1 = *(const short8*)(smem + ((rtb+1)*16 + lr) * 1232 + s * 64 + qoff);
    short8 a2 = *(const short8*)(smem + ((rtb+2)*16 + lr) * 1232 + s * 64 + qoff);
    short8 a3 = *(const short8*)(smem + ((rtb+3)*16 + lr) * 1232 + s * 64 + qoff);
    short8 n0, n1;
    if (s < 18){
      n0 = w1f8[((s+1) * 16 + c0 + 0) * 64 + lane];
      n1 = w1f8[((s+1) * 16 + c0 + 1) * 64 + lane];
    }
    acc[0] = __builtin_amdgcn_mfma_f32_16x16x32_bf16(a0, b0, acc[0], 0, 0, 0);
    acc[1] = __builtin_amdgcn_mfma_f32_16x16x32_bf16(a1, b0, acc[1], 0, 0, 0);
    acc[2] = __builtin_amdgcn_mfma_f32_16x16x32_bf16(a2, b0, acc[2], 0, 0, 0);
    acc[3] = __builtin_amdgcn_mfma_f32_16x16x32_bf16(a3, b0, acc[3], 0, 0, 0);
    acc[4] = __builtin_amdgcn_mfma_f32_16x16x32_bf16(a0, b1v, acc[4], 0, 0, 0);
    acc[5] = __builtin_amdgcn_mfma_f32_16x16x32_bf16(a1, b1v, acc[5], 0, 0, 0);
    acc[6] = __builtin_amdgcn_mfma_f32_16x16x32_bf16(a2, b1v, acc[6], 0, 0, 0);
    acc[7] = __builtin_amdgcn_mfma_f32_16x16x32_bf16(a3, b1v, acc[7], 0, 0, 0);
    b0 = n0; b1v = n1;
  }
  __syncthreads();   // edge_in reads done; alias LDS as H

  // H = gelu(acc + b1), bf16, stride 264 (528 B; 33x16 -> conflict-free)
  unsigned short* H = (unsigned short*)smem;
  #pragma unroll
  for (int c = 0; c < 2; ++c){
    int n = (c0 + c) * 16 + lr;
    float bias = b1[n];
    #pragma unroll
    for (int r = 0; r < 4; ++r){
      #pragma unroll
      for (int i = 0; i < 4; ++i){
        int m = (rtb + r) * 16 + quad * 4 + i;   // C/D: row = quad*4+reg, col = lane&15
        H[m * 264 + n] = f2bf(gelu_t(acc[c*4 + r][i] + bias));
      }
    }
  }
  __syncthreads();

  // ---- GEMM2: (128x256) x (256x128), 1 coltile (16 cols) per wave ----
  int c2 = w >> 1;
  f32x4 acc2[4];
  #pragma unroll
  for (int i = 0; i < 4; ++i) acc2[i] = (f32x4){0.f, 0.f, 0.f, 0.f};
  const short8* w2f8 = (const short8*)w2f;
  short8 bb = w2f8[c2 * 64 + lane];
  for (int s = 0; s < 8; ++s){
    short8 a0 = *(const short8*)(smem + ((rtb+0)*16 + lr) * 528 + s * 64 + qoff);
    short8 a1 = *(const short8*)(smem + ((rtb+1)*16 + lr) * 528 + s * 64 + qoff);
    short8 a2 = *(const short8*)(smem + ((rtb+2)*16 + lr) * 528 + s * 64 + qoff);
    short8 a3 = *(const short8*)(smem + ((rtb+3)*16 + lr) * 528 + s * 64 + qoff);
    short8 bn;
    if (s < 7) bn = w2f8[((s+1) * 8 + c2) * 64 + lane];
    acc2[0] = __builtin_amdgcn_mfma_f32_16x16x32_bf16(a0, bb, acc2[0], 0, 0, 0);
    acc2[1] = __builtin_amdgcn_mfma_f32_16x16x32_bf16(a1, bb, acc2[1], 0, 0, 0);
    acc2[2] = __builtin_amdgcn_mfma_f32_16x16x32_bf16(a2, bb, acc2[2], 0, 0, 0);
    acc2[3] = __builtin_amdgcn_mfma_f32_16x16x32_bf16(a3, bb, acc2[3], 0, 0, 0);
    bb = bn;
  }
  __syncthreads();   // H reads done; alias LDS as O (f32, stride 140)

  float* O = (float*)smem;
  {
    int n2 = c2 * 16 + lr;
    float bias = b2[n2];
    #pragma unroll
    for (int r = 0; r < 4; ++r){
      #pragma unroll
      for (int i = 0; i < 4; ++i){
        int m = (rtb + r) * 16 + quad * 4 + i;
        O[m * 140 + n2] = acc2[r][i] + bias;
      }
    }
  }
  __syncthreads();
  // coalesced full-line stores: 128 rows x 512 B
  float* og = outp + (size_t)e0 * 128;
  #pragma unroll
  for (int i = 0; i < 4; ++i){
    int cid = tid + 1024 * i;
    int m = cid >> 5, ch = cid & 31;
    f32x4 v = *(const f32x4*)(O + m * 140 + ch * 4);
    *(f32x4*)(og + m * 128 + ch * 4) = v;
  }
}

extern "C" void kernel_launch(void* const* d_in, const int* in_sizes, int n_in,
                              void* d_out, int out_size, void* d_ws, size_t ws_size,
                              hipStream_t stream) {
  const float* emb    = (const float*)d_in[0];
  const float* ts     = (const float*)d_in[1];
  const float* coords = (const float*)d_in[2];
  const float* tf     = (const float*)d_in[3];
  const float* cf     = (const float*)d_in[4];
  const float* w1r    = (const float*)d_in[5];
  const float* b1r    = (const float*)d_in[6];
  const float* w2r    = (const float*)d_in[7];
  const float* b2r    = (const float*)d_in[8];
  const float* wg     = (const float*)d_in[9];
  const float* w1e    = (const float*)d_in[10];
  const float* b1e    = (const float*)d_in[11];
  const float* w2e    = (const float*)d_in[12];
  const float* b2e    = (const float*)d_in[13];
  const int* resi     = (const int*)d_in[14];
  const int* chain    = (const int*)d_in[15];
  const int* gia      = (const int*)d_in[16];
  const int* gib      = (const int*)d_in[17];
  const int* pid      = (const int*)d_in[18];

  char* ws = (char*)d_ws;
  float* RT            = (float*)(ws + WS_RT);
  unsigned short* REPB = (unsigned short*)(ws + WS_REPB);
  unsigned short* W1F  = (unsigned short*)(ws + WS_W1F);
  unsigned short* W2F  = (unsigned short*)(ws + WS_W2F);
  float* outp          = (float*)d_out;

  hipLaunchKernelGGL(prep_k, dim3(224), dim3(256), 0, stream,
                     emb, ts, tf, w1r, b1r, w2r, b2r, REPB,
                     coords, RT, wg, w1e, W1F, w2e, W2F);
  hipLaunchKernelGGL(edge_k, dim3(1040), dim3(1024), 0, stream,
                     REPB, RT, cf, resi, chain, gia, gib, pid, W1F, W2F, b1e, b2e, outp);
}

// Round 5
// 253.811 us; speedup vs baseline: 1.2982x; 1.0111x over previous
//
#include <hip/hip_runtime.h>

// BindingFormer fused pipeline for MI355X (gfx950), round 5.
// r4 post-mortem: LDS 158.7 KB -> 1 block/CU -> all phases (features, GEMM1,
// gelu epilogue, GEMM2, O-stage) serialize at barriers with zero overlap.
// Fix: M=64 edges/block, 512 thr (8 waves), LDS 79,360 B -> 2 blocks/CU so
// block A's epilogue/feature phases overlap block B's MFMA loop (m114).
// Wave tiles: GEMM1 1 rowgroup x 8 colgroups (B has no intra-block redundancy,
// 32 KB/step/CU from L2 unchanged); GEMM2 1 coltile/wave.

typedef __attribute__((ext_vector_type(8))) short short8;  // 8 x bf16 (4 VGPRs)
typedef __attribute__((ext_vector_type(4))) float f32x4;   // MFMA accumulator

#define TWO_PI 6.283185307179586f
#define E_AB_TOT 131072

// ws layout (bytes)
#define WS_RT    0         // frames: 1024 x 12 f32            = 49152
#define WS_REPB  49152     // rep bf16 1024x256                = 524288
#define WS_W1F   573440    // swizzled W1' 19*16*64*8 bf16     = 311296
#define WS_W2F   884736    // swizzled W2  8*8*64*8 bf16       = 65536

__device__ __forceinline__ unsigned short f2bf(float x){
  unsigned int u = __float_as_uint(x);
  u += 0x7fffu + ((u >> 16) & 1u);            // RTNE
  return (unsigned short)(u >> 16);
}

__device__ __forceinline__ float gelu_t(float x){
  float z = 0.7978845608028654f * (x + 0.044715f * x * x * x);
  float e = __expf(2.0f * z);
  float t = 1.0f - 2.0f / (e + 1.0f);         // tanh(z), robust at +/-inf
  return 0.5f * x * (1.0f + t);
}

// ---------- merged prep: rep MLP (blk 0-127) | frames (128-131) |
//            swz2 (132-147) | swz1 w/ inline wg1 (148-223) -------------------
__global__ __launch_bounds__(256) void prep_k(
    const float* __restrict__ emb, const float* __restrict__ ts,
    const float* __restrict__ tf,  const float* __restrict__ w1,
    const float* __restrict__ b1,  const float* __restrict__ w2,
    const float* __restrict__ b2,  unsigned short* __restrict__ repb,
    const float* __restrict__ coords, float* __restrict__ RT,
    const float* __restrict__ wg, const float* __restrict__ w1e,
    unsigned short* __restrict__ w1f,
    const float* __restrict__ w2e, unsigned short* __restrict__ w2f){
  __shared__ float xt[288 * 12];   // rep part only
  __shared__ float ht[256 * 12];
  int blk = blockIdx.x, tid = threadIdx.x;
  if (blk < 128){                   // ---- node MLP, 8 nodes/block ----
    int n0 = blk * 8;
    #pragma unroll
    for (int nd = 0; nd < 8; ++nd)
      xt[tid * 12 + nd] = emb[(n0 + nd) * 256 + tid];
    {
      int nd = tid >> 5, j = tid & 31;
      float ang = TWO_PI * ts[n0 + nd] * tf[j & 15];
      float s, c; __sincosf(ang, &s, &c);
      xt[(256 + j) * 12 + nd] = (j < 16) ? s : c;
    }
    __syncthreads();
    float acc[8];
    float bias1 = b1[tid];
    #pragma unroll
    for (int nd = 0; nd < 8; ++nd) acc[nd] = bias1;
    #pragma unroll 4
    for (int k = 0; k < 288; ++k){
      float w = w1[k * 256 + tid];
      f32x4 xa = *(const f32x4*)&xt[k * 12];
      f32x4 xb = *(const f32x4*)&xt[k * 12 + 4];
      acc[0] += xa[0]*w; acc[1] += xa[1]*w; acc[2] += xa[2]*w; acc[3] += xa[3]*w;
      acc[4] += xb[0]*w; acc[5] += xb[1]*w; acc[6] += xb[2]*w; acc[7] += xb[3]*w;
    }
    #pragma unroll
    for (int nd = 0; nd < 8; ++nd) ht[tid * 12 + nd] = gelu_t(acc[nd]);
    __syncthreads();
    float acc2[8];
    float bias2 = b2[tid];
    #pragma unroll
    for (int nd = 0; nd < 8; ++nd) acc2[nd] = bias2;
    #pragma unroll 4
    for (int k = 0; k < 256; ++k){
      float w = w2[k * 256 + tid];
      f32x4 ha = *(const f32x4*)&ht[k * 12];
      f32x4 hb = *(const f32x4*)&ht[k * 12 + 4];
      acc2[0] += ha[0]*w; acc2[1] += ha[1]*w; acc2[2] += ha[2]*w; acc2[3] += ha[3]*w;
      acc2[4] += hb[0]*w; acc2[5] += hb[1]*w; acc2[6] += hb[2]*w; acc2[7] += hb[3]*w;
    }
    #pragma unroll
    for (int nd = 0; nd < 8; ++nd)
      repb[(n0 + nd) * 256 + tid] = f2bf(acc2[nd] + xt[tid * 12 + nd]);
  } else if (blk < 132){            // ---- frames ----
    int n = (blk - 128) * 256 + tid;
    const float* p = coords + n * 9;
    float ax=p[0],ay=p[1],az=p[2], bx=p[3],by=p[4],bz=p[5], cx=p[6],cy=p[7],cz=p[8];
    float v1x=cx-bx, v1y=cy-by, v1z=cz-bz;
    float v2x=ax-bx, v2y=ay-by, v2z=az-bz;
    float n1 = sqrtf(v1x*v1x+v1y*v1y+v1z*v1z) + 1e-6f;
    float e1x=v1x/n1, e1y=v1y/n1, e1z=v1z/n1;
    float dp = e1x*v2x + e1y*v2y + e1z*v2z;
    float u2x=v2x-e1x*dp, u2y=v2y-e1y*dp, u2z=v2z-e1z*dp;
    float n2 = sqrtf(u2x*u2x+u2y*u2y+u2z*u2z) + 1e-6f;
    float e2x=u2x/n2, e2y=u2y/n2, e2z=u2z/n2;
    float* r = RT + n * 12;
    r[0]=e1x; r[1]=e2x; r[2]=e1y*e2z - e1z*e2y;
    r[3]=e1y; r[4]=e2y; r[5]=e1z*e2x - e1x*e2z;
    r[6]=e1z; r[7]=e2z; r[8]=e1x*e2y - e1y*e2x;
    r[9]=bx;  r[10]=by; r[11]=bz;
  } else if (blk < 148){            // ---- swz2: W2 (256x128) -> B-frag ----
    int u = (blk - 132) * 4 + (tid >> 6);   // 0..63
    int lane = tid & 63;
    int s = u >> 3, c = u & 7;
    int n  = c * 16 + (lane & 15);
    int kb = s * 32 + (lane >> 4) * 8;
    unsigned short* o = w2f + (((s * 8 + c) * 64) + lane) * 8;
    for (int j = 0; j < 8; ++j)
      o[j] = f2bf(w2e[(kb + j) * 128 + n]);
  } else {                          // ---- swz1: W1' (608x256) -> B-frag ----
    // K: [0:27 geom=wg@w1e[0:128] | 27:91 rope (w1e 128:192) | 91:96 zero
    //     | 96:352 rep_src (192:448) | 352:608 rep_dst (448:704)]
    int u = (blk - 148) * 4 + (tid >> 6);   // 0..303
    int lane = tid & 63;
    int s = u >> 4, c = u & 15;
    int n  = c * 16 + (lane & 15);
    int kb = s * 32 + (lane >> 4) * 8;
    unsigned short* o = w1f + (((s * 16 + c) * 64) + lane) * 8;
    for (int j = 0; j < 8; ++j){
      int k = kb + j;
      float val;
      if (k < 27){                  // inline wg1: w_geom[k] . w1e[0:128, n]
        val = 0.f;
        for (int j2 = 0; j2 < 128; ++j2) val += wg[k * 128 + j2] * w1e[j2 * 256 + n];
      }
      else if (k < 91)  val = w1e[(128 + k - 27)  * 256 + n];
      else if (k < 96)  val = 0.f;
      else if (k < 352) val = w1e[(192 + k - 96)  * 256 + n];
      else              val = w1e[(448 + k - 352) * 256 + n];
      o[j] = f2bf(val);
    }
  }
}

// ---------- fused edge kernel: 64 edges/block, 512 thr (8 waves) -----------
// LDS 79,360 B -> 2 blocks/CU. GEMM1: each wave = 4 rowtiles x 2 coltiles
// (c0 = w*2), B distinct per wave. GEMM2: 1 coltile/wave.
__global__ __launch_bounds__(512, 4) void edge_k(
    const unsigned short* __restrict__ repb, const float* __restrict__ RT,
    const float* __restrict__ cf,
    const int* __restrict__ resi, const int* __restrict__ chain,
    const int* __restrict__ gia,  const int* __restrict__ gib,
    const int* __restrict__ pid,
    const unsigned short* __restrict__ w1f, const unsigned short* __restrict__ w2f,
    const float* __restrict__ bias1, const float* __restrict__ bias2,
    float* __restrict__ outp)
{
  __shared__ __align__(16) char smem[78848];   // 64 rows x 1232 B edge_in
  __shared__ int lsrc[64];
  __shared__ int ldst[64];

  int tid = threadIdx.x;
  int e0  = blockIdx.x * 64;

  if (tid < 64){
    int e = e0 + tid, s_, d_;
    if (e < E_AB_TOT){ s_ = gia[e]; d_ = gib[e]; }
    else {
      int i = e - E_AB_TOT;
      int b = i >> 10, w_ = i & 1023;
      s_ = pid[b * 32 + (w_ >> 5)];
      d_ = pid[b * 32 + (w_ & 31)];
    }
    lsrc[tid] = s_; ldst[tid] = d_;
  }
  __syncthreads();

  // issue rep-gather loads (64 edges x 2 x 512 B), overlap with features
  uint4 g[8];
  int ged[8], gpart[8], goff[8];
  {
    const uint4* rep4 = (const uint4*)repb;
    #pragma unroll
    for (int i = 0; i < 8; ++i){
      int cid = tid + 512 * i;
      ged[i] = cid >> 6; gpart[i] = (cid >> 5) & 1; goff[i] = cid & 31;
      int row = gpart[i] ? ldst[ged[i]] : lsrc[ged[i]];
      g[i] = rep4[row * 32 + goff[i]];
    }
  }

  // features: 8 threads/edge, 12 cols each (cols 0..95)
  {
    int ed = tid >> 3, slot = tid & 7;
    int s_ = lsrc[ed], d_ = ldst[ed];
    unsigned short* row = (unsigned short*)(smem + ed * 1232);
    float disp = ((float)resi[s_] - (float)resi[d_]) * 0.125f;
    float inv  = (chain[s_] == chain[d_]) ? 1.f / (fabsf(disp) + 1.f) : 0.f;
    const float* Rs = RT + s_ * 12;
    const float* Rd = RT + d_ * 12;
    float dx = Rd[9]-Rs[9], dy = Rd[10]-Rs[10], dz = Rd[11]-Rs[11];
    float dist = sqrtf(dx*dx + dy*dy + dz*dz + 1e-6f);
    float invd = 1.f / (dist + 1.f);
    #pragma unroll
    for (int q = 0; q < 12; ++q){
      int c = slot * 12 + q;
      float val;
      if (c < 15){                               // rbf
        float z = (dist - (float)c * (20.f / 14.f)) * (15.f / 20.f);
        val = __expf(-0.5f * z * z);
      } else if (c < 24){                        // relrot (a-major)
        int idx = c - 15, a = idx / 3, b_ = idx - a * 3;
        val = Rs[a]*Rd[b_] + Rs[3+a]*Rd[3+b_] + Rs[6+a]*Rd[6+b_];
      } else if (c < 27){                        // local
        int k = c - 24;
        val = (Rs[k]*dx + Rs[3+k]*dy + Rs[6+k]*dz) * invd;
      } else if (c < 91){                        // rope
        int j2 = c - 27;
        float ang = TWO_PI * disp * cf[j2 & 31];
        val = ((j2 < 32) ? __sinf(ang) : __cosf(ang)) * inv;
      } else val = 0.f;
      row[c] = f2bf(val);
    }
  }

  // store gathered rep rows (cols 96..607)
  #pragma unroll
  for (int i = 0; i < 8; ++i)
    *(uint4*)(smem + ged[i] * 1232 + 192 + gpart[i] * 512 + goff[i] * 16) = g[i];
  __syncthreads();

  // ---- GEMM1: (64x608) x (608x256) ----
  int w    = tid >> 6, lane = tid & 63;
  int c0   = w * 2;                 // 2 coltiles (32 cols) per wave, distinct
  int lr   = lane & 15;
  int quad = lane >> 4, qoff = quad * 16;
  f32x4 acc[8];                     // [c*4 + rowtile]
  #pragma unroll
  for (int i = 0; i < 8; ++i) acc[i] = (f32x4){0.f, 0.f, 0.f, 0.f};
  const short8* w1f8 = (const short8*)w1f;

  short8 b0 = w1f8[(c0 + 0) * 64 + lane];
  short8 b1v = w1f8[(c0 + 1) * 64 + lane];
  for (int s = 0; s < 19; ++s){
    short8 a0 = *(const short8*)(smem + ( 0 + lr) * 1232 + s * 64 + qoff);
    short8 a1 = *(const short8*)(smem + (16 + lr) * 1232 + s * 64 + qoff);
    short8 a2 = *(const short8*)(smem + (32 + lr) * 1232 + s * 64 + qoff);
    short8 a3 = *(const short8*)(smem + (48 + lr) * 1232 + s * 64 + qoff);
    short8 n0, n1;
    if (s < 18){
      n0 = w1f8[((s+1) * 16 + c0 + 0) * 64 + lane];
      n1 = w1f8[((s+1) * 16 + c0 + 1) * 64 + lane];
    }
    acc[0] = __builtin_amdgcn_mfma_f32_16x16x32_bf16(a0, b0, acc[0], 0, 0, 0);
    acc[1] = __builtin_amdgcn_mfma_f32_16x16x32_bf16(a1, b0, acc[1], 0, 0, 0);
    acc[2] = __builtin_amdgcn_mfma_f32_16x16x32_bf16(a2, b0, acc[2], 0, 0, 0);
    acc[3] = __builtin_amdgcn_mfma_f32_16x16x32_bf16(a3, b0, acc[3], 0, 0, 0);
    acc[4] = __builtin_amdgcn_mfma_f32_16x16x32_bf16(a0, b1v, acc[4], 0, 0, 0);
    acc[5] = __builtin_amdgcn_mfma_f32_16x16x32_bf16(a1, b1v, acc[5], 0, 0, 0);
    acc[6] = __builtin_amdgcn_mfma_f32_16x16x32_bf16(a2, b1v, acc[6], 0, 0, 0);
    acc[7] = __builtin_amdgcn_mfma_f32_16x16x32_bf16(a3, b1v, acc[7], 0, 0, 0);
    b0 = n0; b1v = n1;
  }
  __syncthreads();   // edge_in reads done; alias LDS as H

  // H = gelu(acc + b1), bf16, stride 264 (528 B)
  unsigned short* H = (unsigned short*)smem;
  #pragma unroll
  for (int c = 0; c < 2; ++c){
    int n = (c0 + c) * 16 + lr;
    float bias = bias1[n];
    #pragma unroll
    for (int i = 0; i < 4; ++i){                 // rowtile
      #pragma unroll
      for (int r = 0; r < 4; ++r){
        int m = i * 16 + quad * 4 + r;           // C/D: row = quad*4+reg, col = lane&15
        H[m * 264 + n] = f2bf(gelu_t(acc[c*4 + i][r] + bias));
      }
    }
  }
  __syncthreads();

  // ---- GEMM2: (64x256) x (256x128), 1 coltile (16 cols) per wave ----
  int c2 = w;
  f32x4 acc2[4];
  #pragma unroll
  for (int i = 0; i < 4; ++i) acc2[i] = (f32x4){0.f, 0.f, 0.f, 0.f};
  const short8* w2f8 = (const short8*)w2f;
  short8 bb = w2f8[c2 * 64 + lane];
  for (int s = 0; s < 8; ++s){
    short8 a0 = *(const short8*)(smem + ( 0 + lr) * 528 + s * 64 + qoff);
    short8 a1 = *(const short8*)(smem + (16 + lr) * 528 + s * 64 + qoff);
    short8 a2 = *(const short8*)(smem + (32 + lr) * 528 + s * 64 + qoff);
    short8 a3 = *(const short8*)(smem + (48 + lr) * 528 + s * 64 + qoff);
    short8 bn;
    if (s < 7) bn = w2f8[((s+1) * 8 + c2) * 64 + lane];
    acc2[0] = __builtin_amdgcn_mfma_f32_16x16x32_bf16(a0, bb, acc2[0], 0, 0, 0);
    acc2[1] = __builtin_amdgcn_mfma_f32_16x16x32_bf16(a1, bb, acc2[1], 0, 0, 0);
    acc2[2] = __builtin_amdgcn_mfma_f32_16x16x32_bf16(a2, bb, acc2[2], 0, 0, 0);
    acc2[3] = __builtin_amdgcn_mfma_f32_16x16x32_bf16(a3, bb, acc2[3], 0, 0, 0);
    bb = bn;
  }
  __syncthreads();   // H reads done; alias LDS as O (f32, stride 140)

  float* O = (float*)smem;
  {
    int n2 = c2 * 16 + lr;
    float bias = bias2[n2];
    #pragma unroll
    for (int i = 0; i < 4; ++i){
      #pragma unroll
      for (int r = 0; r < 4; ++r){
        int m = i * 16 + quad * 4 + r;
        O[m * 140 + n2] = acc2[i][r] + bias;
      }
    }
  }
  __syncthreads();
  // coalesced full-line stores: 64 rows x 512 B
  float* og = outp + (size_t)e0 * 128;
  #pragma unroll
  for (int i = 0; i < 4; ++i){
    int cid = tid + 512 * i;
    int m = cid >> 5, ch = cid & 31;
    f32x4 v = *(const f32x4*)(O + m * 140 + ch * 4);
    *(f32x4*)(og + m * 128 + ch * 4) = v;
  }
}

extern "C" void kernel_launch(void* const* d_in, const int* in_sizes, int n_in,
                              void* d_out, int out_size, void* d_ws, size_t ws_size,
                              hipStream_t stream) {
  const float* emb    = (const float*)d_in[0];
  const float* ts     = (const float*)d_in[1];
  const float* coords = (const float*)d_in[2];
  const float* tf     = (const float*)d_in[3];
  const float* cf     = (const float*)d_in[4];
  const float* w1r    = (const float*)d_in[5];
  const float* b1r    = (const float*)d_in[6];
  const float* w2r    = (const float*)d_in[7];
  const float* b2r    = (const float*)d_in[8];
  const float* wg     = (const float*)d_in[9];
  const float* w1e    = (const float*)d_in[10];
  const float* b1e    = (const float*)d_in[11];
  const float* w2e    = (const float*)d_in[12];
  const float* b2e    = (const float*)d_in[13];
  const int* resi     = (const int*)d_in[14];
  const int* chain    = (const int*)d_in[15];
  const int* gia      = (const int*)d_in[16];
  const int* gib      = (const int*)d_in[17];
  const int* pid      = (const int*)d_in[18];

  char* ws = (char*)d_ws;
  float* RT            = (float*)(ws + WS_RT);
  unsigned short* REPB = (unsigned short*)(ws + WS_REPB);
  unsigned short* W1F  = (unsigned short*)(ws + WS_W1F);
  unsigned short* W2F  = (unsigned short*)(ws + WS_W2F);
  float* outp          = (float*)d_out;

  hipLaunchKernelGGL(prep_k, dim3(224), dim3(256), 0, stream,
                     emb, ts, tf, w1r, b1r, w2r, b2r, REPB,
                     coords, RT, wg, w1e, W1F, w2e, W2F);
  hipLaunchKernelGGL(edge_k, dim3(2080), dim3(512), 0, stream,
                     REPB, RT, cf, resi, chain, gia, gib, pid, W1F, W2F, b1e, b2e, outp);
}

// Round 6
// 252.892 us; speedup vs baseline: 1.3029x; 1.0036x over previous
//
#include <hip/hip_runtime.h>

// BindingFormer fused pipeline for MI355X (gfx950), round 6.
// r5 post-mortem: VALU-bound (120k cyc/CU vs 52k MFMA) — H epilogue did
// scalar gelu+RTNE+u16-write on 32 values/thread because C/D frags run along
// m (rows). Fix: TRANSPOSED GEMMs (weights as A-operand, edge/H rows as B):
// C/D now has 4 consecutive n per lane -> b64 H writes, f32x4 bias, direct
// dwordx4 global out (O-stage removed), sigmoid-form gelu (x*sigma(2z)).
// W1F/W2F bytes unchanged (A-frag layout == B-frag layout per lane).

typedef __attribute__((ext_vector_type(8))) short short8;  // 8 x bf16 (4 VGPRs)
typedef __attribute__((ext_vector_type(4))) float f32x4;   // MFMA accumulator

#define TWO_PI 6.283185307179586f
#define E_AB_TOT 131072

// ws layout (bytes)
#define WS_RT    0         // frames: 1024 x 12 f32            = 49152
#define WS_REPB  49152     // rep bf16 1024x256                = 524288
#define WS_W1F   573440    // swizzled W1' 19*16*64*8 bf16     = 311296
#define WS_W2F   884736    // swizzled W2  8*8*64*8 bf16       = 65536

__device__ __forceinline__ unsigned short f2bf(float x){
  unsigned int u = __float_as_uint(x);
  u += 0x7fffu + ((u >> 16) & 1u);            // RTNE
  return (unsigned short)(u >> 16);
}

// pack two f32 -> two bf16 (RTNE) in one u32 via v_perm
__device__ __forceinline__ unsigned int pack_bf16(float lo, float hi){
  unsigned int ul = __float_as_uint(lo), uh = __float_as_uint(hi);
  ul += 0x7fffu + ((ul >> 16) & 1u);
  uh += 0x7fffu + ((uh >> 16) & 1u);
  return __builtin_amdgcn_perm(uh, ul, 0x07060302);  // {uh[31:16], ul[31:16]}
}

// gelu tanh-form == x * sigmoid(2z), z = 0.79788456(x + 0.044715 x^3)
// exp(-2z) = exp2(x * (a + b*x^2)), a = -2.30220847, b = a*0.044715
__device__ __forceinline__ float gelu_s(float x){
  float s = x * x;
  float w = x * __builtin_fmaf(-0.1029437f, s, -2.30220847f);
  float e = __builtin_exp2f(w);
  return x * __builtin_amdgcn_rcpf(1.0f + e);
}

// ---------- merged prep: rep MLP (blk 0-127) | frames (128-131) |
//            swz2 (132-147) | swz1 w/ inline wg1 (148-223) -------------------
__global__ __launch_bounds__(256) void prep_k(
    const float* __restrict__ emb, const float* __restrict__ ts,
    const float* __restrict__ tf,  const float* __restrict__ w1,
    const float* __restrict__ b1,  const float* __restrict__ w2,
    const float* __restrict__ b2,  unsigned short* __restrict__ repb,
    const float* __restrict__ coords, float* __restrict__ RT,
    const float* __restrict__ wg, const float* __restrict__ w1e,
    unsigned short* __restrict__ w1f,
    const float* __restrict__ w2e, unsigned short* __restrict__ w2f){
  __shared__ float xt[288 * 12];   // rep part only
  __shared__ float ht[256 * 12];
  int blk = blockIdx.x, tid = threadIdx.x;
  if (blk < 128){                   // ---- node MLP, 8 nodes/block ----
    int n0 = blk * 8;
    #pragma unroll
    for (int nd = 0; nd < 8; ++nd)
      xt[tid * 12 + nd] = emb[(n0 + nd) * 256 + tid];
    {
      int nd = tid >> 5, j = tid & 31;
      float ang = TWO_PI * ts[n0 + nd] * tf[j & 15];
      float s, c; __sincosf(ang, &s, &c);
      xt[(256 + j) * 12 + nd] = (j < 16) ? s : c;
    }
    __syncthreads();
    float acc[8];
    float bias1 = b1[tid];
    #pragma unroll
    for (int nd = 0; nd < 8; ++nd) acc[nd] = bias1;
    #pragma unroll 4
    for (int k = 0; k < 288; ++k){
      float w = w1[k * 256 + tid];
      f32x4 xa = *(const f32x4*)&xt[k * 12];
      f32x4 xb = *(const f32x4*)&xt[k * 12 + 4];
      acc[0] += xa[0]*w; acc[1] += xa[1]*w; acc[2] += xa[2]*w; acc[3] += xa[3]*w;
      acc[4] += xb[0]*w; acc[5] += xb[1]*w; acc[6] += xb[2]*w; acc[7] += xb[3]*w;
    }
    #pragma unroll
    for (int nd = 0; nd < 8; ++nd) ht[tid * 12 + nd] = gelu_s(acc[nd]);
    __syncthreads();
    float acc2[8];
    float bias2 = b2[tid];
    #pragma unroll
    for (int nd = 0; nd < 8; ++nd) acc2[nd] = bias2;
    #pragma unroll 4
    for (int k = 0; k < 256; ++k){
      float w = w2[k * 256 + tid];
      f32x4 ha = *(const f32x4*)&ht[k * 12];
      f32x4 hb = *(const f32x4*)&ht[k * 12 + 4];
      acc2[0] += ha[0]*w; acc2[1] += ha[1]*w; acc2[2] += ha[2]*w; acc2[3] += ha[3]*w;
      acc2[4] += hb[0]*w; acc2[5] += hb[1]*w; acc2[6] += hb[2]*w; acc2[7] += hb[3]*w;
    }
    #pragma unroll
    for (int nd = 0; nd < 8; ++nd)
      repb[(n0 + nd) * 256 + tid] = f2bf(acc2[nd] + xt[tid * 12 + nd]);
  } else if (blk < 132){            // ---- frames ----
    int n = (blk - 128) * 256 + tid;
    const float* p = coords + n * 9;
    float ax=p[0],ay=p[1],az=p[2], bx=p[3],by=p[4],bz=p[5], cx=p[6],cy=p[7],cz=p[8];
    float v1x=cx-bx, v1y=cy-by, v1z=cz-bz;
    float v2x=ax-bx, v2y=ay-by, v2z=az-bz;
    float n1 = sqrtf(v1x*v1x+v1y*v1y+v1z*v1z) + 1e-6f;
    float e1x=v1x/n1, e1y=v1y/n1, e1z=v1z/n1;
    float dp = e1x*v2x + e1y*v2y + e1z*v2z;
    float u2x=v2x-e1x*dp, u2y=v2y-e1y*dp, u2z=v2z-e1z*dp;
    float n2 = sqrtf(u2x*u2x+u2y*u2y+u2z*u2z) + 1e-6f;
    float e2x=u2x/n2, e2y=u2y/n2, e2z=u2z/n2;
    float* r = RT + n * 12;
    r[0]=e1x; r[1]=e2x; r[2]=e1y*e2z - e1z*e2y;
    r[3]=e1y; r[4]=e2y; r[5]=e1z*e2x - e1x*e2z;
    r[6]=e1z; r[7]=e2z; r[8]=e1x*e2y - e1y*e2x;
    r[9]=bx;  r[10]=by; r[11]=bz;
  } else if (blk < 148){            // ---- swz2: W2 (256x128) -> frag ----
    int u = (blk - 132) * 4 + (tid >> 6);   // 0..63
    int lane = tid & 63;
    int s = u >> 3, c = u & 7;
    int n  = c * 16 + (lane & 15);
    int kb = s * 32 + (lane >> 4) * 8;
    unsigned short* o = w2f + (((s * 8 + c) * 64) + lane) * 8;
    for (int j = 0; j < 8; ++j)
      o[j] = f2bf(w2e[(kb + j) * 128 + n]);
  } else {                          // ---- swz1: W1' (608x256) -> frag ----
    // K: [0:27 geom=wg@w1e[0:128] | 27:91 rope (w1e 128:192) | 91:96 zero
    //     | 96:352 rep_src (192:448) | 352:608 rep_dst (448:704)]
    int u = (blk - 148) * 4 + (tid >> 6);   // 0..303
    int lane = tid & 63;
    int s = u >> 4, c = u & 15;
    int n  = c * 16 + (lane & 15);
    int kb = s * 32 + (lane >> 4) * 8;
    unsigned short* o = w1f + (((s * 16 + c) * 64) + lane) * 8;
    for (int j = 0; j < 8; ++j){
      int k = kb + j;
      float val;
      if (k < 27){                  // inline wg1: w_geom[k] . w1e[0:128, n]
        val = 0.f;
        for (int j2 = 0; j2 < 128; ++j2) val += wg[k * 128 + j2] * w1e[j2 * 256 + n];
      }
      else if (k < 91)  val = w1e[(128 + k - 27)  * 256 + n];
      else if (k < 96)  val = 0.f;
      else if (k < 352) val = w1e[(192 + k - 96)  * 256 + n];
      else              val = w1e[(448 + k - 352) * 256 + n];
      o[j] = f2bf(val);
    }
  }
}

// ---------- fused edge kernel: 64 edges/block, 512 thr (8 waves) -----------
// TRANSPOSED: mfma(A=weight frag, B=edge/H row frag) -> D[col=edge, row=n].
// GEMM1: wave w owns n-tiles {2w, 2w+1} x 4 edge-tiles. GEMM2: n-tile w x 4.
__global__ __launch_bounds__(512, 4) void edge_k(
    const unsigned short* __restrict__ repb, const float* __restrict__ RT,
    const float* __restrict__ cf,
    const int* __restrict__ resi, const int* __restrict__ chain,
    const int* __restrict__ gia,  const int* __restrict__ gib,
    const int* __restrict__ pid,
    const unsigned short* __restrict__ w1f, const unsigned short* __restrict__ w2f,
    const float* __restrict__ bias1, const float* __restrict__ bias2,
    float* __restrict__ outp)
{
  __shared__ __align__(16) char smem[78848];   // 64 rows x 1232 B edge_in
  __shared__ int lsrc[64];
  __shared__ int ldst[64];

  int tid = threadIdx.x;
  int e0  = blockIdx.x * 64;

  if (tid < 64){
    int e = e0 + tid, s_, d_;
    if (e < E_AB_TOT){ s_ = gia[e]; d_ = gib[e]; }
    else {
      int i = e - E_AB_TOT;
      int b = i >> 10, w_ = i & 1023;
      s_ = pid[b * 32 + (w_ >> 5)];
      d_ = pid[b * 32 + (w_ & 31)];
    }
    lsrc[tid] = s_; ldst[tid] = d_;
  }
  __syncthreads();

  // issue rep-gather loads (64 edges x 2 x 512 B), overlap with features
  uint4 g[8];
  int ged[8], gpart[8], goff[8];
  {
    const uint4* rep4 = (const uint4*)repb;
    #pragma unroll
    for (int i = 0; i < 8; ++i){
      int cid = tid + 512 * i;
      ged[i] = cid >> 6; gpart[i] = (cid >> 5) & 1; goff[i] = cid & 31;
      int row = gpart[i] ? ldst[ged[i]] : lsrc[ged[i]];
      g[i] = rep4[row * 32 + goff[i]];
    }
  }

  // features: 8 threads/edge, 12 cols each (cols 0..95)
  {
    int ed = tid >> 3, slot = tid & 7;
    int s_ = lsrc[ed], d_ = ldst[ed];
    unsigned short* row = (unsigned short*)(smem + ed * 1232);
    float disp = ((float)resi[s_] - (float)resi[d_]) * 0.125f;
    float inv  = (chain[s_] == chain[d_]) ? 1.f / (fabsf(disp) + 1.f) : 0.f;
    const float* Rs = RT + s_ * 12;
    const float* Rd = RT + d_ * 12;
    float dx = Rd[9]-Rs[9], dy = Rd[10]-Rs[10], dz = Rd[11]-Rs[11];
    float dist = sqrtf(dx*dx + dy*dy + dz*dz + 1e-6f);
    float invd = 1.f / (dist + 1.f);
    #pragma unroll
    for (int q = 0; q < 12; ++q){
      int c = slot * 12 + q;
      float val;
      if (c < 15){                               // rbf
        float z = (dist - (float)c * (20.f / 14.f)) * (15.f / 20.f);
        val = __expf(-0.5f * z * z);
      } else if (c < 24){                        // relrot (a-major)
        int idx = c - 15, a = idx / 3, b_ = idx - a * 3;
        val = Rs[a]*Rd[b_] + Rs[3+a]*Rd[3+b_] + Rs[6+a]*Rd[6+b_];
      } else if (c < 27){                        // local
        int k = c - 24;
        val = (Rs[k]*dx + Rs[3+k]*dy + Rs[6+k]*dz) * invd;
      } else if (c < 91){                        // rope
        int j2 = c - 27;
        float ang = TWO_PI * disp * cf[j2 & 31];
        val = ((j2 < 32) ? __sinf(ang) : __cosf(ang)) * inv;
      } else val = 0.f;
      row[c] = f2bf(val);
    }
  }

  // store gathered rep rows (cols 96..607)
  #pragma unroll
  for (int i = 0; i < 8; ++i)
    *(uint4*)(smem + ged[i] * 1232 + 192 + gpart[i] * 512 + goff[i] * 16) = g[i];
  __syncthreads();

  // ---- GEMM1 (transposed): D[n][e] = W1'^T x edge_in^T ----
  int w    = tid >> 6, lane = tid & 63;
  int c0   = w * 2;                 // 2 n-tiles per wave
  int lr   = lane & 15;             // edge within e-tile
  int quad = lane >> 4, qoff = quad * 16;
  f32x4 acc[8];                     // [c*4 + etile]
  #pragma unroll
  for (int i = 0; i < 8; ++i) acc[i] = (f32x4){0.f, 0.f, 0.f, 0.f};
  const short8* w1f8 = (const short8*)w1f;

  short8 a0 = w1f8[(c0 + 0) * 64 + lane];     // weight frags (A-operand)
  short8 a1 = w1f8[(c0 + 1) * 64 + lane];
  for (int s = 0; s < 19; ++s){
    short8 be0 = *(const short8*)(smem + ( 0 + lr) * 1232 + s * 64 + qoff);
    short8 be1 = *(const short8*)(smem + (16 + lr) * 1232 + s * 64 + qoff);
    short8 be2 = *(const short8*)(smem + (32 + lr) * 1232 + s * 64 + qoff);
    short8 be3 = *(const short8*)(smem + (48 + lr) * 1232 + s * 64 + qoff);
    short8 n0, n1;
    if (s < 18){
      n0 = w1f8[((s+1) * 16 + c0 + 0) * 64 + lane];
      n1 = w1f8[((s+1) * 16 + c0 + 1) * 64 + lane];
    }
    acc[0] = __builtin_amdgcn_mfma_f32_16x16x32_bf16(a0, be0, acc[0], 0, 0, 0);
    acc[1] = __builtin_amdgcn_mfma_f32_16x16x32_bf16(a0, be1, acc[1], 0, 0, 0);
    acc[2] = __builtin_amdgcn_mfma_f32_16x16x32_bf16(a0, be2, acc[2], 0, 0, 0);
    acc[3] = __builtin_amdgcn_mfma_f32_16x16x32_bf16(a0, be3, acc[3], 0, 0, 0);
    acc[4] = __builtin_amdgcn_mfma_f32_16x16x32_bf16(a1, be0, acc[4], 0, 0, 0);
    acc[5] = __builtin_amdgcn_mfma_f32_16x16x32_bf16(a1, be1, acc[5], 0, 0, 0);
    acc[6] = __builtin_amdgcn_mfma_f32_16x16x32_bf16(a1, be2, acc[6], 0, 0, 0);
    acc[7] = __builtin_amdgcn_mfma_f32_16x16x32_bf16(a1, be3, acc[7], 0, 0, 0);
    a0 = n0; a1 = n1;
  }
  __syncthreads();   // edge_in reads done; alias LDS as H (64 x 264 bf16)

  // H[e][n] = gelu(D[n][e] + b1[n]); lane has 4 consecutive n -> b64 writes
  {
    char* Hb = smem;
    #pragma unroll
    for (int c = 0; c < 2; ++c){
      int n = (c0 + c) * 16 + quad * 4;
      f32x4 bz = *(const f32x4*)(bias1 + n);
      #pragma unroll
      for (int t = 0; t < 4; ++t){
        int e = t * 16 + lr;
        float v0 = gelu_s(acc[c*4 + t][0] + bz[0]);
        float v1 = gelu_s(acc[c*4 + t][1] + bz[1]);
        float v2 = gelu_s(acc[c*4 + t][2] + bz[2]);
        float v3 = gelu_s(acc[c*4 + t][3] + bz[3]);
        uint2 p; p.x = pack_bf16(v0, v1); p.y = pack_bf16(v2, v3);
        *(uint2*)(Hb + e * 528 + n * 2) = p;
      }
    }
  }
  __syncthreads();

  // ---- GEMM2 (transposed): D[n][e] = W2^T x H^T, n-tile = w ----
  f32x4 acc2[4];
  #pragma unroll
  for (int i = 0; i < 4; ++i) acc2[i] = (f32x4){0.f, 0.f, 0.f, 0.f};
  const short8* w2f8 = (const short8*)w2f;
  short8 aa = w2f8[w * 64 + lane];
  for (int s = 0; s < 8; ++s){
    short8 h0 = *(const short8*)(smem + ( 0 + lr) * 528 + s * 64 + qoff);
    short8 h1 = *(const short8*)(smem + (16 + lr) * 528 + s * 64 + qoff);
    short8 h2 = *(const short8*)(smem + (32 + lr) * 528 + s * 64 + qoff);
    short8 h3 = *(const short8*)(smem + (48 + lr) * 528 + s * 64 + qoff);
    short8 an;
    if (s < 7) an = w2f8[((s+1) * 8 + w) * 64 + lane];
    acc2[0] = __builtin_amdgcn_mfma_f32_16x16x32_bf16(aa, h0, acc2[0], 0, 0, 0);
    acc2[1] = __builtin_amdgcn_mfma_f32_16x16x32_bf16(aa, h1, acc2[1], 0, 0, 0);
    acc2[2] = __builtin_amdgcn_mfma_f32_16x16x32_bf16(aa, h2, acc2[2], 0, 0, 0);
    acc2[3] = __builtin_amdgcn_mfma_f32_16x16x32_bf16(aa, h3, acc2[3], 0, 0, 0);
    aa = an;
  }

  // direct f32 output: lane has out[e][n..n+3] -> global dwordx4
  {
    int n = w * 16 + quad * 4;
    f32x4 bz = *(const f32x4*)(bias2 + n);
    float* og = outp + (size_t)e0 * 128 + n;
    #pragma unroll
    for (int t = 0; t < 4; ++t){
      int e = t * 16 + lr;
      f32x4 v;
      v[0] = acc2[t][0] + bz[0]; v[1] = acc2[t][1] + bz[1];
      v[2] = acc2[t][2] + bz[2]; v[3] = acc2[t][3] + bz[3];
      *(f32x4*)(og + (size_t)e * 128) = v;
    }
  }
}

extern "C" void kernel_launch(void* const* d_in, const int* in_sizes, int n_in,
                              void* d_out, int out_size, void* d_ws, size_t ws_size,
                              hipStream_t stream) {
  const float* emb    = (const float*)d_in[0];
  const float* ts     = (const float*)d_in[1];
  const float* coords = (const float*)d_in[2];
  const float* tf     = (const float*)d_in[3];
  const float* cf     = (const float*)d_in[4];
  const float* w1r    = (const float*)d_in[5];
  const float* b1r    = (const float*)d_in[6];
  const float* w2r    = (const float*)d_in[7];
  const float* b2r    = (const float*)d_in[8];
  const float* wg     = (const float*)d_in[9];
  const float* w1e    = (const float*)d_in[10];
  const float* b1e    = (const float*)d_in[11];
  const float* w2e    = (const float*)d_in[12];
  const float* b2e    = (const float*)d_in[13];
  const int* resi     = (const int*)d_in[14];
  const int* chain    = (const int*)d_in[15];
  const int* gia      = (const int*)d_in[16];
  const int* gib      = (const int*)d_in[17];
  const int* pid      = (const int*)d_in[18];

  char* ws = (char*)d_ws;
  float* RT            = (float*)(ws + WS_RT);
  unsigned short* REPB = (unsigned short*)(ws + WS_REPB);
  unsigned short* W1F  = (unsigned short*)(ws + WS_W1F);
  unsigned short* W2F  = (unsigned short*)(ws + WS_W2F);
  float* outp          = (float*)d_out;

  hipLaunchKernelGGL(prep_k, dim3(224), dim3(256), 0, stream,
                     emb, ts, tf, w1r, b1r, w2r, b2r, REPB,
                     coords, RT, wg, w1e, W1F, w2e, W2F);
  hipLaunchKernelGGL(edge_k, dim3(2080), dim3(512), 0, stream,
                     REPB, RT, cf, resi, chain, gia, gib, pid, W1F, W2F, b1e, b2e, outp);
}